// Round 4
// baseline (852.562 us; speedup 1.0000x reference)
//
#include <hip/hip_runtime.h>
#include <hip/hip_bf16.h>

typedef __attribute__((ext_vector_type(8))) __bf16 bf16x8;
typedef __attribute__((ext_vector_type(4))) float f32x4;

#define NBATCH 32
#define MDIM 8192
#define CDIM 512
#define DDIM 64
#define KCLU 8
#define MT 128
#define NT 80     // 64 d-cols + 8 logit-cols (W_lin@W_red) + 8 zero pad

// ws layout:
static constexpr int ACC_OFF   = 0;       // float[32*8*64] vlad accumulators
static constexpr int SUMA_OFF  = 16384;   // float[32*8]    sum_m a
static constexpr int DOTWB_OFF = 16640;   // float[8]       W_lin . b_red
static constexpr size_t BHI_OFF = 66592;  // bytes: ushort[80*512] B hi (16B aligned)
static constexpr size_t BLO_OFF = BHI_OFF + (size_t)NT * CDIM * 2;

__device__ __forceinline__ unsigned short f32_bf16_rne(float x) {
  unsigned u = __float_as_uint(x);
  u += 0x7fffu + ((u >> 16) & 1u);
  return (unsigned short)(u >> 16);
}

// hi = truncated-bf16(v) (cheap), lo = rne-bf16(v - hi): v = hi + lo + O(2^-17 v)
__device__ __forceinline__ void split2(float v, unsigned short& h, unsigned short& l) {
  unsigned u = __float_as_uint(v);
  unsigned hu = u & 0xffff0000u;
  h = (unsigned short)(hu >> 16);
  l = f32_bf16_rne(v - __uint_as_float(hu));
}

__global__ void netvlad_prep(const float* __restrict__ W_red,
                             const float* __restrict__ b_red,
                             const float* __restrict__ W_lin,
                             const float* __restrict__ b_lin,
                             float* __restrict__ ws_f,
                             unsigned short* __restrict__ Bhi,
                             unsigned short* __restrict__ Blo) {
  int gid = blockIdx.x * 256 + threadIdx.x;
  if (gid < NT * CDIM) {
    int n = gid >> 9, cc = gid & 511;
    float v = 0.f;
    if (n < 64) {
      v = W_red[gid];
    } else if (n < 72) {
      int k = n - 64;
      float s = 0.f;
      for (int d = 0; d < 64; ++d) s += W_lin[k * 64 + d] * W_red[d * 512 + cc];
      v = s;
    }
    unsigned short h, l;
    split2(v, h, l);
    Bhi[gid] = h;
    Blo[gid] = l;
  } else if (gid < NT * CDIM + 16640) {
    ws_f[gid - NT * CDIM] = 0.f;   // zero acc + suma (float idx 0..16639)
  } else if (gid < NT * CDIM + 16640 + 8) {
    int k = gid - (NT * CDIM + 16640);
    float s = 0.f;
    for (int d = 0; d < 64; ++d) s += W_lin[k * 64 + d] * b_red[d];
    ws_f[DOTWB_OFF + k] = s;
  }
}

__device__ __forceinline__ bf16x8 cvt8_rne(const f32x4& p0, const f32x4& p1) {
  union { unsigned u[4]; bf16x8 v; } r;
  r.u[0] = (unsigned)f32_bf16_rne(p0[0]) | ((unsigned)f32_bf16_rne(p0[1]) << 16);
  r.u[1] = (unsigned)f32_bf16_rne(p0[2]) | ((unsigned)f32_bf16_rne(p0[3]) << 16);
  r.u[2] = (unsigned)f32_bf16_rne(p1[0]) | ((unsigned)f32_bf16_rne(p1[1]) << 16);
  r.u[3] = (unsigned)f32_bf16_rne(p1[2]) | ((unsigned)f32_bf16_rne(p1[3]) << 16);
  return r.v;
}

// No LDS staging, no K-loop barriers: A (x tile) and B fragments are loaded
// straight from global in MFMA fragment order. A rows: per-lane 32B chunks,
// the wave covers 16 rows x 128B contiguous -> fully coalesced one-pass HBM
// read of x. B chunk per kc is 10 KB, L1/L2-resident.
__global__ __launch_bounds__(256, 3)
void netvlad_main(const float* __restrict__ x,
                  const float* __restrict__ b_red,
                  const float* __restrict__ b_lin,
                  float* __restrict__ ws_f,
                  const unsigned short* __restrict__ Bhi_g,
                  const unsigned short* __restrict__ Blo_g) {
  __shared__ float redv[4 * KCLU * DDIM];
  __shared__ float reds[4 * KCLU];

  const int tid = threadIdx.x;
  const int bb  = blockIdx.y;
  const int m0  = blockIdx.x * MT;
  const int w = tid >> 6;
  const int l = tid & 63;
  const int q = l >> 4;
  const int c = l & 15;

  f32x4 acc[2][5];
#pragma unroll
  for (int tm = 0; tm < 2; ++tm)
#pragma unroll
    for (int ct = 0; ct < 5; ++ct) acc[tm][ct] = (f32x4){0.f, 0.f, 0.f, 0.f};

  const float dw = (c < 8) ? ws_f[DOTWB_OFF + c] : 0.f;
  const float bl = (c < 8) ? b_lin[c] : 0.f;
  float bred[4];
#pragma unroll
  for (int ct = 0; ct < 4; ++ct) bred[ct] = b_red[ct * 16 + c];

  // per-lane fragment base pointers
  const float* a0p = x + ((size_t)(bb * MDIM + m0 + w * 32 + c)) * CDIM + q * 8;
  const float* a1p = a0p + 16 * CDIM;
  const unsigned short* bp = (size_t)(c) * CDIM + q * 8 + (const unsigned short*)0 + 0;
  // (bp is just an offset trick; compute real addresses below)
  const size_t boff = (size_t)c * CDIM + q * 8;

#pragma unroll 2
  for (int kc = 0; kc < CDIM / 32; ++kc) {
    const int kb = kc * 32;
    // A fragments: 8 fp32 each, convert to bf16 rne
    f32x4 a0lo = *(const f32x4*)(a0p + kb);
    f32x4 a0hi = *(const f32x4*)(a0p + kb + 4);
    f32x4 a1lo = *(const f32x4*)(a1p + kb);
    f32x4 a1hi = *(const f32x4*)(a1p + kb + 4);
    // B fragments: direct 16B bf16 loads (hi and lo planes)
    bf16x8 bh[5], blv[5];
#pragma unroll
    for (int ct = 0; ct < 5; ++ct) {
      const size_t ro = boff + (size_t)(ct * 16) * CDIM + kb;
      bh[ct]  = *(const bf16x8*)(Bhi_g + ro);
      blv[ct] = *(const bf16x8*)(Blo_g + ro);
    }
    bf16x8 a0 = cvt8_rne(a0lo, a0hi);
    bf16x8 a1 = cvt8_rne(a1lo, a1hi);
#pragma unroll
    for (int ct = 0; ct < 5; ++ct) {
      acc[0][ct] = __builtin_amdgcn_mfma_f32_16x16x32_bf16(a0, bh[ct],  acc[0][ct], 0, 0, 0);
      acc[0][ct] = __builtin_amdgcn_mfma_f32_16x16x32_bf16(a0, blv[ct], acc[0][ct], 0, 0, 0);
      acc[1][ct] = __builtin_amdgcn_mfma_f32_16x16x32_bf16(a1, bh[ct],  acc[1][ct], 0, 0, 0);
      acc[1][ct] = __builtin_amdgcn_mfma_f32_16x16x32_bf16(a1, blv[ct], acc[1][ct], 0, 0, 0);
    }
  }
  (void)bp;

  // ---- fused epilogue: bias, l2norm, softmax, VLAD partial accumulation ----
  // C/D layout: col = ct*16 + c, row(within tile) = q*4 + r
  float va[8][4];
#pragma unroll
  for (int k = 0; k < 8; ++k)
#pragma unroll
    for (int j = 0; j < 4; ++j) va[k][j] = 0.f;
  float suma_l = 0.f;

#pragma unroll
  for (int tm = 0; tm < 2; ++tm) {
#pragma unroll
    for (int r = 0; r < 4; ++r) {
      float y0 = acc[tm][0][r] + bred[0];
      float y1 = acc[tm][1][r] + bred[1];
      float y2 = acc[tm][2][r] + bred[2];
      float y3 = acc[tm][3][r] + bred[3];
      float sq = y0 * y0 + y1 * y1 + y2 * y2 + y3 * y3;
      sq += __shfl_xor(sq, 1); sq += __shfl_xor(sq, 2);
      sq += __shfl_xor(sq, 4); sq += __shfl_xor(sq, 8);
      const float rinv = 1.0f / fmaxf(sqrtf(sq), 1e-12f);
      // logits came through the GEMM (col-tile 4, lanes c<8 = cluster c)
      const float u  = acc[tm][4][r] + dw;
      const float lg = rinv * u + bl;
      float e = (c < 8) ? __expf(lg) : 0.f;
      float s = e;
      s += __shfl_xor(s, 1); s += __shfl_xor(s, 2); s += __shfl_xor(s, 4);
      const float a  = (c < 8) ? e / s : 0.f;
      suma_l += a;
      const float ae = a * rinv;   // fold rinv into assignment weight
#pragma unroll
      for (int k = 0; k < 8; ++k) {
        const float aek = __shfl(ae, (l & 48) + k);
        va[k][0] += aek * y0; va[k][1] += aek * y1;
        va[k][2] += aek * y2; va[k][3] += aek * y3;
      }
    }
  }
  // reduce across the 4 quads (rows) of the wave
#pragma unroll
  for (int k = 0; k < 8; ++k)
#pragma unroll
    for (int j = 0; j < 4; ++j) {
      va[k][j] += __shfl_xor(va[k][j], 16);
      va[k][j] += __shfl_xor(va[k][j], 32);
    }
  suma_l += __shfl_xor(suma_l, 16);
  suma_l += __shfl_xor(suma_l, 32);

  if (q == 0) {
#pragma unroll
    for (int k = 0; k < 8; ++k)
#pragma unroll
      for (int j = 0; j < 4; ++j)
        redv[(w * KCLU + k) * DDIM + j * 16 + c] = va[k][j];
    if (c < 8) reds[w * KCLU + c] = suma_l;
  }
  __syncthreads();
  for (int idx = tid; idx < KCLU * DDIM; idx += 256) {
    float v = redv[idx] + redv[KCLU * DDIM + idx] +
              redv[2 * KCLU * DDIM + idx] + redv[3 * KCLU * DDIM + idx];
    atomicAdd(&ws_f[ACC_OFF + bb * KCLU * DDIM + idx], v);
  }
  if (tid < KCLU) {
    float v = reds[tid] + reds[KCLU + tid] + reds[2 * KCLU + tid] + reds[3 * KCLU + tid];
    atomicAdd(&ws_f[SUMA_OFF + bb * KCLU + tid], v);
  }
}

__global__ void netvlad_finish(const float* __restrict__ ws_f,
                               const float* __restrict__ centroids,
                               float* __restrict__ out) {
  const int bb = blockIdx.x;
  const int t = threadIdx.x;          // 512 threads: wave w == cluster k
  const int k = t >> 6, d = t & 63;
  __shared__ float s8[8];
  const float suma = ws_f[SUMA_OFF + bb * KCLU + k];
  float v = ws_f[ACC_OFF + (bb * KCLU + k) * DDIM + d] - centroids[k * DDIM + d] * suma;
  float sq = v * v;
#pragma unroll
  for (int off = 1; off < 64; off <<= 1) sq += __shfl_xor(sq, off);
  const float rinv = 1.0f / fmaxf(sqrtf(sq), 1e-12f);
  const float vn = v * rinv;
  if (d == 0) s8[k] = sq * rinv * rinv;
  __syncthreads();
  float g = 0.f;
#pragma unroll
  for (int i = 0; i < 8; ++i) g += s8[i];
  const float gr = 1.0f / fmaxf(sqrtf(g), 1e-12f);
  out[bb * 512 + t] = vn * gr;
}

extern "C" void kernel_launch(void* const* d_in, const int* in_sizes, int n_in,
                              void* d_out, int out_size, void* d_ws, size_t ws_size,
                              hipStream_t stream) {
  const float* x         = (const float*)d_in[0];
  // d_in[1] = mask: all-ones, unused by the reference math
  const float* W_red     = (const float*)d_in[2];
  const float* b_red     = (const float*)d_in[3];
  const float* W_lin     = (const float*)d_in[4];
  const float* b_lin     = (const float*)d_in[5];
  const float* centroids = (const float*)d_in[6];
  float* ws_f = (float*)d_ws;
  unsigned short* Bhi = (unsigned short*)((char*)d_ws + BHI_OFF);
  unsigned short* Blo = (unsigned short*)((char*)d_ws + BLO_OFF);
  float* out = (float*)d_out;

  int prep_tasks = NT * CDIM + 16640 + 8;
  netvlad_prep<<<(prep_tasks + 255) / 256, 256, 0, stream>>>(
      W_red, b_red, W_lin, b_lin, ws_f, Bhi, Blo);

  dim3 grid(MDIM / MT, NBATCH);
  netvlad_main<<<grid, 256, 0, stream>>>(x, b_red, b_lin, ws_f, Bhi, Blo);

  netvlad_finish<<<NBATCH, 512, 0, stream>>>(ws_f, centroids, out);
}

// Round 5
// 717.806 us; speedup vs baseline: 1.1877x; 1.1877x over previous
//
#include <hip/hip_runtime.h>
#include <hip/hip_bf16.h>

typedef __attribute__((ext_vector_type(8))) __bf16 bf16x8;
typedef __attribute__((ext_vector_type(4))) float f32x4;

#define NBATCH 32
#define MDIM 8192
#define CDIM 512
#define DDIM 64
#define KCLU 8
#define MT 128
#define KCH 32
#define ASTR 40   // KCH + 8 pad (bf16 elems); 80 B row stride -> 2-way bank alias (free)
#define NT 80     // 64 d-cols + 8 logit-cols (W_lin@W_red) + 8 zero pad

// ws layout:
static constexpr int ACC_OFF   = 0;       // float[32*8*64] vlad accumulators
static constexpr int SUMA_OFF  = 16384;   // float[32*8]    sum_m a
static constexpr int DOTWB_OFF = 16640;   // float[8]       W_lin . b_red
static constexpr size_t BHI_OFF = 66592;  // bytes: ushort[80*512] B hi (16B aligned)
static constexpr size_t BLO_OFF = BHI_OFF + (size_t)NT * CDIM * 2;

__device__ __forceinline__ unsigned short f32_bf16_rne(float x) {
  unsigned u = __float_as_uint(x);
  u += 0x7fffu + ((u >> 16) & 1u);
  return (unsigned short)(u >> 16);
}

// hi = truncated-bf16(v), lo = rne-bf16(v - hi): v = hi + lo + O(2^-17 v)
__device__ __forceinline__ void split2(float v, unsigned short& h, unsigned short& l) {
  unsigned u = __float_as_uint(v);
  unsigned hu = u & 0xffff0000u;
  h = (unsigned short)(hu >> 16);
  l = f32_bf16_rne(v - __uint_as_float(hu));
}

__global__ void netvlad_prep(const float* __restrict__ W_red,
                             const float* __restrict__ b_red,
                             const float* __restrict__ W_lin,
                             const float* __restrict__ b_lin,
                             float* __restrict__ ws_f,
                             unsigned short* __restrict__ Bhi,
                             unsigned short* __restrict__ Blo) {
  int gid = blockIdx.x * 256 + threadIdx.x;
  if (gid < NT * CDIM) {
    int n = gid >> 9, cc = gid & 511;
    float v = 0.f;
    if (n < 64) {
      v = W_red[gid];
    } else if (n < 72) {
      int k = n - 64;
      float s = 0.f;
      for (int d = 0; d < 64; ++d) s += W_lin[k * 64 + d] * W_red[d * 512 + cc];
      v = s;
    }
    unsigned short h, l;
    split2(v, h, l);
    Bhi[gid] = h;
    Blo[gid] = l;
  } else if (gid < NT * CDIM + 16640) {
    ws_f[gid - NT * CDIM] = 0.f;   // zero acc + suma (float idx 0..16639)
  } else if (gid < NT * CDIM + 16640 + 8) {
    int k = gid - (NT * CDIM + 16640);
    float s = 0.f;
    for (int d = 0; d < 64; ++d) s += W_lin[k * 64 + d] * b_red[d];
    ws_f[DOTWB_OFF + k] = s;
  }
}

// pack 8 fp32 -> 8 bf16 (RNE) as uint4, via packed hw cvt
__device__ __forceinline__ uint4 pack8_bf16(const f32x4& p0, const f32x4& p1) {
  union { __hip_bfloat162 h2[4]; uint4 u; } r;
  r.h2[0] = __float22bfloat162_rn(float2{p0[0], p0[1]});
  r.h2[1] = __float22bfloat162_rn(float2{p0[2], p0[3]});
  r.h2[2] = __float22bfloat162_rn(float2{p1[0], p1[1]});
  r.h2[3] = __float22bfloat162_rn(float2{p1[2], p1[3]});
  return r.u;
}

__global__ __launch_bounds__(256, 4)
void netvlad_main(const float* __restrict__ x,
                  const float* __restrict__ b_red,
                  const float* __restrict__ b_lin,
                  float* __restrict__ ws_f,
                  const unsigned short* __restrict__ Bhi_g,
                  const unsigned short* __restrict__ Blo_g) {
  __shared__ unsigned short Ahi[MT * ASTR];
  __shared__ unsigned short Bhi[NT * ASTR];
  __shared__ unsigned short Blo[NT * ASTR];
  __shared__ float redv[4 * KCLU * DDIM];
  __shared__ float reds[4 * KCLU];

  const int tid = threadIdx.x;
  const int bb  = blockIdx.y;
  const int m0  = blockIdx.x * MT;
  const int w = tid >> 6;
  const int l = tid & 63;
  const int q = l >> 4;
  const int c = l & 15;

  f32x4 acc[2][5];
#pragma unroll
  for (int tm = 0; tm < 2; ++tm)
#pragma unroll
    for (int ct = 0; ct < 5; ++ct) acc[tm][ct] = (f32x4){0.f, 0.f, 0.f, 0.f};

  const float dw = (c < 8) ? ws_f[DOTWB_OFF + c] : 0.f;
  const float bl = (c < 8) ? b_lin[c] : 0.f;
  float bred[4];
#pragma unroll
  for (int ct = 0; ct < 4; ++ct) bred[ct] = b_red[ct * 16 + c];

  for (int kc = 0; kc < CDIM / KCH; ++kc) {
    __syncthreads();
    const int kbase = kc * KCH;
    // ---- stage A: 128 rows x 32 k -> bf16 rne ----
#pragma unroll
    for (int i = 0; i < 2; ++i) {
      const int id = tid + 256 * i;          // 0..511
      const int row = id >> 2, g = id & 3;
      const float* src = x + ((size_t)(bb * MDIM + m0 + row)) * CDIM + kbase + g * 8;
      f32x4 p0 = *(const f32x4*)src;
      f32x4 p1 = *(const f32x4*)(src + 4);
      *(uint4*)&Ahi[row * ASTR + g * 8] = pack8_bf16(p0, p1);
    }
    // ---- stage B: 80 rows x 32 k, hi+lo planes, already bf16 in ws ----
#pragma unroll
    for (int i = 0; i < 3; ++i) {
      const int id = tid + 256 * i;          // 0..767, valid < 640
      if (id < 640) {
        const int half = (id >= 320);
        const int id2 = id - half * 320;
        const int row = id2 >> 2, g = id2 & 3;
        const unsigned short* src = (half ? Blo_g : Bhi_g) + (size_t)row * CDIM + kbase + g * 8;
        uint4 p = *(const uint4*)src;
        unsigned short* dst = (half ? Blo : Bhi) + row * ASTR + g * 8;
        *(uint4*)dst = p;
      }
    }
    __syncthreads();
    // ---- MFMA: 2 row-tiles x 5 col-tiles x (B-hi + B-lo) ----
    bf16x8 ah[2], bh[5], blv[5];
#pragma unroll
    for (int tm = 0; tm < 2; ++tm) {
      const int ro = (w * 32 + tm * 16 + c) * ASTR + q * 8;
      ah[tm] = *(const bf16x8*)&Ahi[ro];
    }
#pragma unroll
    for (int ct = 0; ct < 5; ++ct) {
      const int ro = (ct * 16 + c) * ASTR + q * 8;
      bh[ct]  = *(const bf16x8*)&Bhi[ro];
      blv[ct] = *(const bf16x8*)&Blo[ro];
    }
#pragma unroll
    for (int tm = 0; tm < 2; ++tm)
#pragma unroll
      for (int ct = 0; ct < 5; ++ct) {
        acc[tm][ct] = __builtin_amdgcn_mfma_f32_16x16x32_bf16(ah[tm], bh[ct],  acc[tm][ct], 0, 0, 0);
        acc[tm][ct] = __builtin_amdgcn_mfma_f32_16x16x32_bf16(ah[tm], blv[ct], acc[tm][ct], 0, 0, 0);
      }
  }

  // ---- fused epilogue: bias, l2norm, softmax, VLAD partial accumulation ----
  // C/D layout: col = ct*16 + c, row(within tile) = q*4 + r
  float va[8][4];
#pragma unroll
  for (int k = 0; k < 8; ++k)
#pragma unroll
    for (int j = 0; j < 4; ++j) va[k][j] = 0.f;
  float suma_l = 0.f;

#pragma unroll
  for (int tm = 0; tm < 2; ++tm) {
#pragma unroll
    for (int r = 0; r < 4; ++r) {
      float y0 = acc[tm][0][r] + bred[0];
      float y1 = acc[tm][1][r] + bred[1];
      float y2 = acc[tm][2][r] + bred[2];
      float y3 = acc[tm][3][r] + bred[3];
      float sq = y0 * y0 + y1 * y1 + y2 * y2 + y3 * y3;
      sq += __shfl_xor(sq, 1); sq += __shfl_xor(sq, 2);
      sq += __shfl_xor(sq, 4); sq += __shfl_xor(sq, 8);
      const float rinv = 1.0f / fmaxf(sqrtf(sq), 1e-12f);
      // logits came through the GEMM (col-tile 4, lanes c<8 = cluster c)
      const float u  = acc[tm][4][r] + dw;
      const float lg = rinv * u + bl;
      float e = (c < 8) ? __expf(lg) : 0.f;
      float s = e;
      s += __shfl_xor(s, 1); s += __shfl_xor(s, 2); s += __shfl_xor(s, 4);
      const float a  = (c < 8) ? e / s : 0.f;
      suma_l += a;
      const float ae = a * rinv;   // fold rinv into assignment weight
#pragma unroll
      for (int k = 0; k < 8; ++k) {
        const float aek = __shfl(ae, (l & 48) + k);
        va[k][0] += aek * y0; va[k][1] += aek * y1;
        va[k][2] += aek * y2; va[k][3] += aek * y3;
      }
    }
  }
  // reduce across the 4 quads (rows) of the wave
#pragma unroll
  for (int k = 0; k < 8; ++k)
#pragma unroll
    for (int j = 0; j < 4; ++j) {
      va[k][j] += __shfl_xor(va[k][j], 16);
      va[k][j] += __shfl_xor(va[k][j], 32);
    }
  suma_l += __shfl_xor(suma_l, 16);
  suma_l += __shfl_xor(suma_l, 32);

  if (q == 0) {
#pragma unroll
    for (int k = 0; k < 8; ++k)
#pragma unroll
      for (int j = 0; j < 4; ++j)
        redv[(w * KCLU + k) * DDIM + j * 16 + c] = va[k][j];
    if (c < 8) reds[w * KCLU + c] = suma_l;
  }
  __syncthreads();
  for (int idx = tid; idx < KCLU * DDIM; idx += 256) {
    float v = redv[idx] + redv[KCLU * DDIM + idx] +
              redv[2 * KCLU * DDIM + idx] + redv[3 * KCLU * DDIM + idx];
    atomicAdd(&ws_f[ACC_OFF + bb * KCLU * DDIM + idx], v);
  }
  if (tid < KCLU) {
    float v = reds[tid] + reds[KCLU + tid] + reds[2 * KCLU + tid] + reds[3 * KCLU + tid];
    atomicAdd(&ws_f[SUMA_OFF + bb * KCLU + tid], v);
  }
}

__global__ void netvlad_finish(const float* __restrict__ ws_f,
                               const float* __restrict__ centroids,
                               float* __restrict__ out) {
  const int bb = blockIdx.x;
  const int t = threadIdx.x;          // 512 threads: wave w == cluster k
  const int k = t >> 6, d = t & 63;
  __shared__ float s8[8];
  const float suma = ws_f[SUMA_OFF + bb * KCLU + k];
  float v = ws_f[ACC_OFF + (bb * KCLU + k) * DDIM + d] - centroids[k * DDIM + d] * suma;
  float sq = v * v;
#pragma unroll
  for (int off = 1; off < 64; off <<= 1) sq += __shfl_xor(sq, off);
  const float rinv = 1.0f / fmaxf(sqrtf(sq), 1e-12f);
  const float vn = v * rinv;
  if (d == 0) s8[k] = sq * rinv * rinv;
  __syncthreads();
  float g = 0.f;
#pragma unroll
  for (int i = 0; i < 8; ++i) g += s8[i];
  const float gr = 1.0f / fmaxf(sqrtf(g), 1e-12f);
  out[bb * 512 + t] = vn * gr;
}

extern "C" void kernel_launch(void* const* d_in, const int* in_sizes, int n_in,
                              void* d_out, int out_size, void* d_ws, size_t ws_size,
                              hipStream_t stream) {
  const float* x         = (const float*)d_in[0];
  // d_in[1] = mask: all-ones, unused by the reference math
  const float* W_red     = (const float*)d_in[2];
  const float* b_red     = (const float*)d_in[3];
  const float* W_lin     = (const float*)d_in[4];
  const float* b_lin     = (const float*)d_in[5];
  const float* centroids = (const float*)d_in[6];
  float* ws_f = (float*)d_ws;
  unsigned short* Bhi = (unsigned short*)((char*)d_ws + BHI_OFF);
  unsigned short* Blo = (unsigned short*)((char*)d_ws + BLO_OFF);
  float* out = (float*)d_out;

  int prep_tasks = NT * CDIM + 16640 + 8;
  netvlad_prep<<<(prep_tasks + 255) / 256, 256, 0, stream>>>(
      W_red, b_red, W_lin, b_lin, ws_f, Bhi, Blo);

  dim3 grid(MDIM / MT, NBATCH);
  netvlad_main<<<grid, 256, 0, stream>>>(x, b_red, b_lin, ws_f, Bhi, Blo);

  netvlad_finish<<<NBATCH, 512, 0, stream>>>(ws_f, centroids, out);
}